// Round 1
// baseline (999.761 us; speedup 1.0000x reference)
//
#include <hip/hip_runtime.h>
#include <math.h>

// Problem constants
#define GS   29
#define GS2  841
#define NCP  24389            // 29^3 control points
#define DW   15
#define PP   225              // DW^2 displacements
#define CH   675              // PP*3 channels per control point
#define CC   8                // feature channels
#define VV   64               // volume side
#define V3   262144           // 64^3

__device__ __forceinline__ void fma4(float4& a, float w, const float4 b) {
    a.x += w * b.x; a.y += w * b.y; a.z += w * b.z; a.w += w * b.w;
}

// feat50 (C,D,H,W) -> (D,H,W,C) channel-last for vectorized corner loads
__global__ __launch_bounds__(256) void transpose_feat(const float* __restrict__ in,
                                                      float* __restrict__ out) {
    int tid = blockIdx.x * 256 + threadIdx.x;
    if (tid >= V3 * CC) return;
    int v = tid >> 3, c = tid & 7;
    out[tid] = in[c * V3 + v];
}

// pdd[n, s] = alpha1 + alpha0 * SSD(fix(n), mov(n, p, k)),  s = p*3+k
__global__ __launch_bounds__(256) void pdd_kernel(const float* __restrict__ f00,   // (C,D,H,W)
                                                  const float* __restrict__ f50t,  // (D,H,W,C)
                                                  const float* __restrict__ grid,  // (N,3) xyz
                                                  const float* __restrict__ shift, // (P,3,3)
                                                  const float* __restrict__ alpha,
                                                  float* __restrict__ pdd) {
    int n = blockIdx.x;
    int tid = threadIdx.x;
    __shared__ __align__(16) float fix[8];

    float gx = grid[n * 3 + 0], gy = grid[n * 3 + 1], gz = grid[n * 3 + 2];

    if (tid < 8) {
        // trilerp feat00 channel 'tid' at grid point, padding_mode='zeros'
        float ix = 0.5f * ((gx + 1.f) * VV - 1.f);
        float iy = 0.5f * ((gy + 1.f) * VV - 1.f);
        float iz = 0.5f * ((gz + 1.f) * VV - 1.f);
        float x0f = floorf(ix), y0f = floorf(iy), z0f = floorf(iz);
        float fx = ix - x0f, fy = iy - y0f, fz = iz - z0f;
        int x0 = (int)x0f, y0 = (int)y0f, z0 = (int)z0f;
        const float* fc = f00 + tid * V3;
        float acc = 0.f;
        for (int dz = 0; dz < 2; dz++) {
            int zi = z0 + dz; float wz = dz ? fz : 1.f - fz;
            for (int dy = 0; dy < 2; dy++) {
                int yi = y0 + dy; float wy = dy ? fy : 1.f - fy;
                for (int dx = 0; dx < 2; dx++) {
                    int xi = x0 + dx; float wx = dx ? fx : 1.f - fx;
                    if (xi >= 0 && xi < VV && yi >= 0 && yi < VV && zi >= 0 && zi < VV)
                        acc += wx * wy * wz * fc[(zi * VV + yi) * VV + xi];
                }
            }
        }
        fix[tid] = acc;
    }
    __syncthreads();

    float4 fA = *(const float4*)&fix[0];
    float4 fB = *(const float4*)&fix[4];
    float a0 = alpha[0], a1 = alpha[1];

    for (int s = tid; s < CH; s += 256) {
        int p = s / 3, k = s - 3 * p;
        const float* sh = shift + p * 9 + k * 3;
        float px = gx + sh[0], py = gy + sh[1], pz = gz + sh[2];
        float ix = 0.5f * ((px + 1.f) * VV - 1.f);
        float iy = 0.5f * ((py + 1.f) * VV - 1.f);
        float iz = 0.5f * ((pz + 1.f) * VV - 1.f);
        float x0f = floorf(ix), y0f = floorf(iy), z0f = floorf(iz);
        float fx = ix - x0f, fy = iy - y0f, fz = iz - z0f;
        int x0 = (int)x0f, y0 = (int)y0f, z0 = (int)z0f;
        int x0c = min(max(x0, 0), VV - 1), x1c = min(max(x0 + 1, 0), VV - 1);
        int y0c = min(max(y0, 0), VV - 1), y1c = min(max(y0 + 1, 0), VV - 1);
        int z0c = min(max(z0, 0), VV - 1), z1c = min(max(z0 + 1, 0), VV - 1);

        float wx0 = 1.f - fx, wx1 = fx;
        float wy0 = 1.f - fy, wy1 = fy;
        float wz0 = 1.f - fz, wz1 = fz;

        float4 m0 = {0, 0, 0, 0}, m1 = {0, 0, 0, 0};
        const float4* q;
        float w;
#define CORNER(ZI, YI, XI, W)                                            \
        q = (const float4*)(f50t + (((ZI) * VV + (YI)) * VV + (XI)) * CC); \
        w = (W); fma4(m0, w, q[0]); fma4(m1, w, q[1]);
        CORNER(z0c, y0c, x0c, wz0 * wy0 * wx0)
        CORNER(z0c, y0c, x1c, wz0 * wy0 * wx1)
        CORNER(z0c, y1c, x0c, wz0 * wy1 * wx0)
        CORNER(z0c, y1c, x1c, wz0 * wy1 * wx1)
        CORNER(z1c, y0c, x0c, wz1 * wy0 * wx0)
        CORNER(z1c, y0c, x1c, wz1 * wy0 * wx1)
        CORNER(z1c, y1c, x0c, wz1 * wy1 * wx0)
        CORNER(z1c, y1c, x1c, wz1 * wy1 * wx1)
#undef CORNER
        float d0 = fA.x - m0.x, d1 = fA.y - m0.y, d2 = fA.z - m0.z, d3 = fA.w - m0.w;
        float d4 = fB.x - m1.x, d5 = fB.y - m1.y, d6 = fB.z - m1.z, d7 = fB.w - m1.w;
        float ssd = d0 * d0 + d1 * d1 + d2 * d2 + d3 * d3 +
                    d4 * d4 + d5 * d5 + d6 * d6 + d7 * d7;
        pdd[n * CH + s] = a1 + a0 * ssd;
    }
}

// Per control point: pad2(edge) -> min3x3 -> avg3x3 over the 15x15 disp plane (per k)
__global__ __launch_bounds__(256) void pool_kernel(const float* __restrict__ in,
                                                   float* __restrict__ out) {
    int n = blockIdx.x;
    int tid = threadIdx.x;
    __shared__ float sin_[CH];
    __shared__ float smn[17 * 17 * 3];
    for (int i = tid; i < CH; i += 256) sin_[i] = in[n * CH + i];
    __syncthreads();
    for (int idx = tid; idx < 17 * 17 * 3; idx += 256) {
        int a = idx / 51; int r = idx - 51 * a; int b = r / 3; int k = r - 3 * b;
        float mn = 1e30f;
        for (int u = 0; u < 3; u++) {
            int hh = min(max(a + u - 2, 0), 14);
            for (int v = 0; v < 3; v++) {
                int ww = min(max(b + v - 2, 0), 14);
                mn = fminf(mn, sin_[(hh * 15 + ww) * 3 + k]);
            }
        }
        smn[idx] = mn;
    }
    __syncthreads();
    for (int s = tid; s < CH; s += 256) {
        int h = s / 45; int r = s - 45 * h; int w = r / 3; int k = r - 3 * w;
        float acc = 0.f;
        for (int a = 0; a < 3; a++)
            for (int b = 0; b < 3; b++)
                acc += smn[(h + a) * 51 + (w + b) * 3 + k];
        out[n * CH + s] = acc * (1.f / 9.f);
    }
}

// grid_smooth = separable 5-tap triangle [1,2,3,2,1]/9 along z then y (edge clamp)
__global__ __launch_bounds__(256) void gs_z(const float* __restrict__ in,
                                            float* __restrict__ out) {
    int i = blockIdx.x * 256 + threadIdx.x;
    if (i >= NCP * CH) return;
    int c = i % CH; int n = i / CH;
    int x = n % GS; int t = n / GS; int y = t % GS; int z = t / GS;
    const float w0 = 1.f / 9.f, w1 = 2.f / 9.f, w2 = 3.f / 9.f;
    float acc = 0.f;
    int zz;
    zz = max(z - 2, 0);      acc += w0 * in[((zz * GS + y) * GS + x) * CH + c];
    zz = max(z - 1, 0);      acc += w1 * in[((zz * GS + y) * GS + x) * CH + c];
    acc += w2 * in[((z * GS + y) * GS + x) * CH + c];
    zz = min(z + 1, GS - 1); acc += w1 * in[((zz * GS + y) * GS + x) * CH + c];
    zz = min(z + 2, GS - 1); acc += w0 * in[((zz * GS + y) * GS + x) * CH + c];
    out[i] = acc;
}

// y-pass fused with cost = a4 + a2*pdd + a3*gs  (in-place on pc)
__global__ __launch_bounds__(256) void gs_y_cost(const float* __restrict__ zt,
                                                 float* pc,   // pdd in, cost out (same buffer)
                                                 const float* __restrict__ alpha) {
    int i = blockIdx.x * 256 + threadIdx.x;
    if (i >= NCP * CH) return;
    int c = i % CH; int n = i / CH;
    int x = n % GS; int t = n / GS; int y = t % GS; int z = t / GS;
    const float w0 = 1.f / 9.f, w1 = 2.f / 9.f, w2 = 3.f / 9.f;
    float acc = 0.f;
    int yy;
    yy = max(y - 2, 0);      acc += w0 * zt[((z * GS + yy) * GS + x) * CH + c];
    yy = max(y - 1, 0);      acc += w1 * zt[((z * GS + yy) * GS + x) * CH + c];
    acc += w2 * zt[((z * GS + y) * GS + x) * CH + c];
    yy = min(y + 1, GS - 1); acc += w1 * zt[((z * GS + yy) * GS + x) * CH + c];
    yy = min(y + 2, GS - 1); acc += w0 * zt[((z * GS + yy) * GS + x) * CH + c];
    pc[i] = alpha[4] + alpha[2] * pc[i] + alpha[3] * acc;
}

// plain y-pass (final grid_smooth -> cost_avg)
__global__ __launch_bounds__(256) void gs_y(const float* __restrict__ zt,
                                            float* __restrict__ out) {
    int i = blockIdx.x * 256 + threadIdx.x;
    if (i >= NCP * CH) return;
    int c = i % CH; int n = i / CH;
    int x = n % GS; int t = n / GS; int y = t % GS; int z = t / GS;
    const float w0 = 1.f / 9.f, w1 = 2.f / 9.f, w2 = 3.f / 9.f;
    float acc = 0.f;
    int yy;
    yy = max(y - 2, 0);      acc += w0 * zt[((z * GS + yy) * GS + x) * CH + c];
    yy = max(y - 1, 0);      acc += w1 * zt[((z * GS + yy) * GS + x) * CH + c];
    acc += w2 * zt[((z * GS + y) * GS + x) * CH + c];
    yy = min(y + 1, GS - 1); acc += w1 * zt[((z * GS + yy) * GS + x) * CH + c];
    yy = min(y + 2, GS - 1); acc += w0 * zt[((z * GS + yy) * GS + x) * CH + c];
    out[i] = acc;
}

// softmax over p (per n,k) + pred_xyz einsum
__global__ __launch_bounds__(256) void softmax_pred(const float* __restrict__ ca,
                                                    const float* __restrict__ shift,
                                                    const float* __restrict__ alpha,
                                                    float* __restrict__ soft,
                                                    float* __restrict__ pred) {
    int n = blockIdx.x;
    int tid = threadIdx.x;
    __shared__ float vals[CH];
    __shared__ float red[256];
    for (int i = tid; i < CH; i += 256) vals[i] = ca[n * CH + i];
    __syncthreads();
    float a5 = alpha[5];
    for (int k = 0; k < 3; k++) {
        float v = -1e30f;
        if (tid < PP) v = -a5 * vals[tid * 3 + k];
        red[tid] = v;
        __syncthreads();
        for (int s2 = 128; s2 > 0; s2 >>= 1) {
            if (tid < s2) red[tid] = fmaxf(red[tid], red[tid + s2]);
            __syncthreads();
        }
        float mx = red[0];
        __syncthreads();
        float e = 0.f;
        if (tid < PP) e = expf(v - mx);
        red[tid] = e;
        __syncthreads();
        for (int s2 = 128; s2 > 0; s2 >>= 1) {
            if (tid < s2) red[tid] += red[tid + s2];
            __syncthreads();
        }
        float sm = red[0];
        __syncthreads();
        if (tid < PP) vals[tid * 3 + k] = e / sm;
        __syncthreads();
    }
    for (int i = tid; i < CH; i += 256) soft[n * CH + i] = vals[i];

    float px = 0.f, py = 0.f, pz = 0.f;
    if (tid < PP) {
        for (int k = 0; k < 3; k++) {
            float s = vals[tid * 3 + k];
            const float* sh = shift + tid * 9 + k * 3;
            px += s * sh[0]; py += s * sh[1]; pz += s * sh[2];
        }
    }
    red[tid] = px; __syncthreads();
    for (int s2 = 128; s2 > 0; s2 >>= 1) { if (tid < s2) red[tid] += red[tid + s2]; __syncthreads(); }
    if (tid == 0) pred[n * 3 + 0] = 0.5f * red[0];
    __syncthreads();
    red[tid] = py; __syncthreads();
    for (int s2 = 128; s2 > 0; s2 >>= 1) { if (tid < s2) red[tid] += red[tid + s2]; __syncthreads(); }
    if (tid == 0) pred[n * 3 + 1] = 0.5f * red[0];
    __syncthreads();
    red[tid] = pz; __syncthreads();
    for (int s2 = 128; s2 > 0; s2 >>= 1) { if (tid < s2) red[tid] += red[tid + s2]; __syncthreads(); }
    if (tid == 0) pred[n * 3 + 2] = 0.5f * red[0];
}

extern "C" void kernel_launch(void* const* d_in, const int* in_sizes, int n_in,
                              void* d_out, int out_size, void* d_ws, size_t ws_size,
                              hipStream_t stream) {
    const float* f00   = (const float*)d_in[0];
    const float* f50   = (const float*)d_in[1];
    // d_in[2] (shift_2d_min) is a broadcast of shift_2d -- unused
    const float* grid  = (const float*)d_in[3];
    const float* shift = (const float*)d_in[4];
    const float* alpha = (const float*)d_in[5];

    float* out0 = (float*)d_out;                   // cost_soft  (N*675)
    float* out1 = out0 + (size_t)NCP * CH;         // pred_xyz   (N*3)
    float* out2 = out1 + (size_t)NCP * 3;          // cost_avg   (N*675)

    float* ws   = (float*)d_ws;
    float* f50t = ws;                              // V3*CC floats
    float* W0   = f50t + (size_t)V3 * CC;          // N*CH
    float* W1   = W0 + (size_t)NCP * CH;           // N*CH
    float* W2   = W1 + (size_t)NCP * CH;           // N*CH

    int tTr = V3 * CC;
    transpose_feat<<<(tTr + 255) / 256, 256, 0, stream>>>(f50, f50t);

    pdd_kernel<<<NCP, 256, 0, stream>>>(f00, f50t, grid, shift, alpha, W0);

    int totNC = NCP * CH;
    int gb = (totNC + 255) / 256;

    pool_kernel<<<NCP, 256, 0, stream>>>(W0, W1);
    gs_z<<<gb, 256, 0, stream>>>(W1, W2);
    gs_y_cost<<<gb, 256, 0, stream>>>(W2, W0, alpha);

    pool_kernel<<<NCP, 256, 0, stream>>>(W0, W1);
    gs_z<<<gb, 256, 0, stream>>>(W1, W2);
    gs_y<<<gb, 256, 0, stream>>>(W2, out2);

    softmax_pred<<<NCP, 256, 0, stream>>>(out2, shift, alpha, out0, out1);
}

// Round 2
// 673.644 us; speedup vs baseline: 1.4841x; 1.4841x over previous
//
#include <hip/hip_runtime.h>
#include <math.h>

// Problem constants
#define GS   29
#define GS2  841
#define NCP  24389            // 29^3 control points
#define DW   15
#define PP   225              // DW^2 displacements
#define CH   675              // PP*3 channels per control point
#define CC   8                // feature channels
#define VV   64               // volume side
#define V3   262144           // 64^3

typedef __attribute__((ext_vector_type(8))) _Float16 half8;

__device__ __forceinline__ float sv(int i) {
    // DR * ((2i+1)/DW - 1)
    return 0.4f * ((2.f * i + 1.f) * (1.f / 15.f) - 1.f);
}

// feat50 (C,D,H,W) fp32 -> two fp16 channel-last volumes:
//   volA: (z,y,x,c)  (x fastest spatial)   for k=0,1 (lane sweep = x)
//   volB: (z,x,y,c)  (y fastest spatial)   for k=2   (lane sweep = y)
__global__ __launch_bounds__(256) void make_vols(const float* __restrict__ in,
                                                 _Float16* __restrict__ volA,
                                                 _Float16* __restrict__ volB) {
    int v = blockIdx.x * 256 + threadIdx.x;
    if (v >= V3) return;
    int z = v >> 12, y = (v >> 6) & 63, x = v & 63;
    half8 h;
#pragma unroll
    for (int c = 0; c < CC; c++) h[c] = (_Float16)in[c * V3 + v];
    *(half8*)(volA + (size_t)v * 8) = h;
    *(half8*)(volB + (size_t)(((z << 6) | x) << 6 | y) * 8) = h;
}

// Block per (n, k). Lane = p (225 of 256 active). fp16 corner loads, one dwordx4 each.
__global__ __launch_bounds__(256) void pdd2(const float* __restrict__ f00,   // (C,D,H,W) fp32
                                            const _Float16* __restrict__ volA,
                                            const _Float16* __restrict__ volB,
                                            const float* __restrict__ grid,  // (N,3) xyz
                                            const float* __restrict__ alpha,
                                            float* __restrict__ pdd) {
    int n = blockIdx.x;
    int k = blockIdx.y;
    int tid = threadIdx.x;
    __shared__ __align__(16) float fix[8];

    float gx = grid[n * 3 + 0], gy = grid[n * 3 + 1], gz = grid[n * 3 + 2];

    if (tid < 8) {
        // trilerp feat00 channel tid at grid point, padding_mode='zeros' (fp32 exact)
        float ix = 0.5f * ((gx + 1.f) * VV - 1.f);
        float iy = 0.5f * ((gy + 1.f) * VV - 1.f);
        float iz = 0.5f * ((gz + 1.f) * VV - 1.f);
        float x0f = floorf(ix), y0f = floorf(iy), z0f = floorf(iz);
        float fx = ix - x0f, fy = iy - y0f, fz = iz - z0f;
        int x0 = (int)x0f, y0 = (int)y0f, z0 = (int)z0f;
        const float* fc = f00 + tid * V3;
        float acc = 0.f;
        for (int dz = 0; dz < 2; dz++) {
            int zi = z0 + dz; float wz = dz ? fz : 1.f - fz;
            for (int dy = 0; dy < 2; dy++) {
                int yi = y0 + dy; float wy = dy ? fy : 1.f - fy;
                for (int dx = 0; dx < 2; dx++) {
                    int xi = x0 + dx; float wx = dx ? fx : 1.f - fx;
                    if (xi >= 0 && xi < VV && yi >= 0 && yi < VV && zi >= 0 && zi < VV)
                        acc += wx * wy * wz * fc[(zi * VV + yi) * VV + xi];
                }
            }
        }
        fix[tid] = acc;
    }
    __syncthreads();
    if (tid >= PP) return;

    int p = tid;
    int h_ = p / 15, w_ = p - 15 * h_;
    float A = sv(h_), B = sv(w_);

    // (u,v,w) axes: u = memory-fastest axis of the chosen volume
    float pu, pv, pw;
    const _Float16* vol;
    if (k == 0)      { pu = gx + B; pv = gy + A; pw = gz;     vol = volA; }
    else if (k == 1) { pu = gx + B; pv = gy;     pw = gz + A; vol = volA; }
    else             { pu = gy + B; pv = gx;     pw = gz + A; vol = volB; }

    float iu = 0.5f * ((pu + 1.f) * VV - 1.f);
    float iv = 0.5f * ((pv + 1.f) * VV - 1.f);
    float iw = 0.5f * ((pw + 1.f) * VV - 1.f);
    float u0f = floorf(iu), v0f = floorf(iv), w0f = floorf(iw);
    float fu = iu - u0f, fv = iv - v0f, fw = iw - w0f;
    int u0 = (int)u0f, v0 = (int)v0f, w0 = (int)w0f;
    int u0c = min(max(u0, 0), VV - 1), u1c = min(max(u0 + 1, 0), VV - 1);
    int v0c = min(max(v0, 0), VV - 1), v1c = min(max(v0 + 1, 0), VV - 1);
    int w0c = min(max(w0, 0), VV - 1), w1c = min(max(w0 + 1, 0), VV - 1);
    float wu0 = 1.f - fu, wu1 = fu;
    float wv0 = 1.f - fv, wv1 = fv;
    float ww0 = 1.f - fw, ww1 = fw;

    float acc[8] = {0.f, 0.f, 0.f, 0.f, 0.f, 0.f, 0.f, 0.f};
#define CORNER(WI, VI, UI, WGT) {                                         \
        half8 hv = *(const half8*)(vol + (size_t)((((WI) << 6) + (VI)) * 64 + (UI)) * 8); \
        float wgt = (WGT);                                                \
        _Pragma("unroll")                                                 \
        for (int c = 0; c < 8; c++) acc[c] += wgt * (float)hv[c];         \
    }
    CORNER(w0c, v0c, u0c, ww0 * wv0 * wu0)
    CORNER(w0c, v0c, u1c, ww0 * wv0 * wu1)
    CORNER(w0c, v1c, u0c, ww0 * wv1 * wu0)
    CORNER(w0c, v1c, u1c, ww0 * wv1 * wu1)
    CORNER(w1c, v0c, u0c, ww1 * wv0 * wu0)
    CORNER(w1c, v0c, u1c, ww1 * wv0 * wu1)
    CORNER(w1c, v1c, u0c, ww1 * wv1 * wu0)
    CORNER(w1c, v1c, u1c, ww1 * wv1 * wu1)
#undef CORNER

    float ssd = 0.f;
#pragma unroll
    for (int c = 0; c < 8; c++) { float d = fix[c] - acc[c]; ssd += d * d; }
    pdd[(size_t)n * CH + p * 3 + k] = alpha[1] + alpha[0] * ssd;
}

// Per control point: pad2(edge) -> min3x3 -> avg3x3 over the 15x15 disp plane (per k)
__global__ __launch_bounds__(256) void pool_kernel(const float* __restrict__ in,
                                                   float* __restrict__ out) {
    int n = blockIdx.x;
    int tid = threadIdx.x;
    __shared__ float sin_[CH];
    __shared__ float smn[17 * 17 * 3];
    for (int i = tid; i < CH; i += 256) sin_[i] = in[(size_t)n * CH + i];
    __syncthreads();
    for (int idx = tid; idx < 17 * 17 * 3; idx += 256) {
        int a = idx / 51; int r = idx - 51 * a; int b = r / 3; int k = r - 3 * b;
        float mn = 1e30f;
        for (int u = 0; u < 3; u++) {
            int hh = min(max(a + u - 2, 0), 14);
            for (int v = 0; v < 3; v++) {
                int ww = min(max(b + v - 2, 0), 14);
                mn = fminf(mn, sin_[(hh * 15 + ww) * 3 + k]);
            }
        }
        smn[idx] = mn;
    }
    __syncthreads();
    for (int s = tid; s < CH; s += 256) {
        int h = s / 45; int r = s - 45 * h; int w = r / 3; int k = r - 3 * w;
        float acc = 0.f;
        for (int a = 0; a < 3; a++)
            for (int b = 0; b < 3; b++)
                acc += smn[(h + a) * 51 + (w + b) * 3 + k];
        out[(size_t)n * CH + s] = acc * (1.f / 9.f);
    }
}

// 5-tap triangle [1,2,3,2,1]/9 along z, sliding window: thread per (y,x,c), march z.
// index(z,y,x,c) = z*ZS + id where id = (y*GS+x)*CH + c
__global__ __launch_bounds__(256) void gs_z2(const float* __restrict__ in,
                                             float* __restrict__ out) {
    const int ZS = GS2 * CH;
    int id = blockIdx.x * 256 + threadIdx.x;
    if (id >= ZS) return;
    const float w0 = 1.f / 9.f, w1 = 2.f / 9.f, w2 = 3.f / 9.f;
    const float* p = in + id;
    float v0 = p[0], v1 = v0, v2 = v0, v3 = p[ZS], v4 = p[2 * (size_t)ZS];
    for (int z = 0; z < GS; z++) {
        out[id + (size_t)z * ZS] = w0 * v0 + w1 * v1 + w2 * v2 + w1 * v3 + w0 * v4;
        v0 = v1; v1 = v2; v2 = v3; v3 = v4;
        int zn = z + 3; if (zn > GS - 1) zn = GS - 1;
        v4 = p[(size_t)zn * ZS];
    }
}

// y-pass fused with cost = a4 + a2*pdd + a3*gs (in-place on pc). Thread per (z,x,c), march y.
__global__ __launch_bounds__(256) void gs_y_cost2(const float* __restrict__ zt,
                                                  float* pc,
                                                  const float* __restrict__ alpha) {
    const int ZS = GS2 * CH, YS = GS * CH;
    int id = blockIdx.x * 256 + threadIdx.x;
    if (id >= GS * YS) return;
    int z = id / YS; int rem = id - z * YS;         // rem = x*CH + c
    size_t base = (size_t)z * ZS + rem;
    const float w0 = 1.f / 9.f, w1 = 2.f / 9.f, w2 = 3.f / 9.f;
    float a2 = alpha[2], a3 = alpha[3], a4 = alpha[4];
    const float* p = zt + base;
    float v0 = p[0], v1 = v0, v2 = v0, v3 = p[YS], v4 = p[2 * (size_t)YS];
    for (int y = 0; y < GS; y++) {
        size_t idx = base + (size_t)y * YS;
        float acc = w0 * v0 + w1 * v1 + w2 * v2 + w1 * v3 + w0 * v4;
        pc[idx] = a4 + a2 * pc[idx] + a3 * acc;
        v0 = v1; v1 = v2; v2 = v3; v3 = v4;
        int yn = y + 3; if (yn > GS - 1) yn = GS - 1;
        v4 = p[(size_t)yn * YS];
    }
}

// plain y-pass (final grid_smooth -> cost_avg)
__global__ __launch_bounds__(256) void gs_y2(const float* __restrict__ zt,
                                             float* __restrict__ out) {
    const int ZS = GS2 * CH, YS = GS * CH;
    int id = blockIdx.x * 256 + threadIdx.x;
    if (id >= GS * YS) return;
    int z = id / YS; int rem = id - z * YS;
    size_t base = (size_t)z * ZS + rem;
    const float w0 = 1.f / 9.f, w1 = 2.f / 9.f, w2 = 3.f / 9.f;
    const float* p = zt + base;
    float v0 = p[0], v1 = v0, v2 = v0, v3 = p[YS], v4 = p[2 * (size_t)YS];
    for (int y = 0; y < GS; y++) {
        out[base + (size_t)y * YS] = w0 * v0 + w1 * v1 + w2 * v2 + w1 * v3 + w0 * v4;
        v0 = v1; v1 = v2; v2 = v3; v3 = v4;
        int yn = y + 3; if (yn > GS - 1) yn = GS - 1;
        v4 = p[(size_t)yn * YS];
    }
}

// softmax over p (per n,k) + pred_xyz einsum — wave-shuffle reductions, one wave per k
__global__ __launch_bounds__(256) void softmax_pred2(const float* __restrict__ ca,
                                                     const float* __restrict__ alpha,
                                                     float* __restrict__ soft,
                                                     float* __restrict__ pred) {
    int n = blockIdx.x;
    int tid = threadIdx.x;
    int wave = tid >> 6, lane = tid & 63;
    __shared__ float vals[CH];
    __shared__ float partial[3][3];   // [k][dim]
    for (int i = tid; i < CH; i += 256) vals[i] = ca[(size_t)n * CH + i];
    __syncthreads();
    float a5 = alpha[5];
    if (wave < 3) {
        int k = wave;
        float v[4], e[4];
        float m = -1e30f;
#pragma unroll
        for (int j = 0; j < 4; j++) {
            int p = lane + 64 * j;
            v[j] = (p < PP) ? -a5 * vals[p * 3 + k] : -1e30f;
            m = fmaxf(m, v[j]);
        }
#pragma unroll
        for (int o = 32; o > 0; o >>= 1) m = fmaxf(m, __shfl_xor(m, o));
        float sum = 0.f;
#pragma unroll
        for (int j = 0; j < 4; j++) {
            int p = lane + 64 * j;
            e[j] = (p < PP) ? __expf(v[j] - m) : 0.f;
            sum += e[j];
        }
#pragma unroll
        for (int o = 32; o > 0; o >>= 1) sum += __shfl_xor(sum, o);
        float inv = 1.f / sum;
        float px = 0.f, py = 0.f, pz = 0.f;
#pragma unroll
        for (int j = 0; j < 4; j++) {
            int p = lane + 64 * j;
            if (p < PP) {
                float s = e[j] * inv;
                vals[p * 3 + k] = s;
                int h_ = p / 15, w_ = p - 15 * h_;
                float A = sv(h_), B = sv(w_);
                if (k == 0)      { px += s * B; py += s * A; }
                else if (k == 1) { px += s * B; pz += s * A; }
                else             { py += s * B; pz += s * A; }
            }
        }
#pragma unroll
        for (int o = 32; o > 0; o >>= 1) {
            px += __shfl_xor(px, o);
            py += __shfl_xor(py, o);
            pz += __shfl_xor(pz, o);
        }
        if (lane == 0) { partial[k][0] = px; partial[k][1] = py; partial[k][2] = pz; }
    }
    __syncthreads();
    if (tid < 3) pred[(size_t)n * 3 + tid] = 0.5f * (partial[0][tid] + partial[1][tid] + partial[2][tid]);
    for (int i = tid; i < CH; i += 256) soft[(size_t)n * CH + i] = vals[i];
}

extern "C" void kernel_launch(void* const* d_in, const int* in_sizes, int n_in,
                              void* d_out, int out_size, void* d_ws, size_t ws_size,
                              hipStream_t stream) {
    const float* f00   = (const float*)d_in[0];
    const float* f50   = (const float*)d_in[1];
    // d_in[2] (shift_2d_min) is a broadcast of shift_2d -- unused
    const float* grid  = (const float*)d_in[3];
    // d_in[4] (shift_2d) recomputed analytically -- unused
    const float* alpha = (const float*)d_in[5];

    float* out0 = (float*)d_out;                   // cost_soft  (N*675)
    float* out1 = out0 + (size_t)NCP * CH;         // pred_xyz   (N*3)
    float* out2 = out1 + (size_t)NCP * 3;          // cost_avg   (N*675)

    char* ws = (char*)d_ws;
    _Float16* volA = (_Float16*)ws;                          // V3*8 halves = 4MB
    _Float16* volB = volA + (size_t)V3 * 8;                  // 4MB
    float* W0 = (float*)(volB + (size_t)V3 * 8);             // N*CH fp32
    float* W1 = W0 + (size_t)NCP * CH;
    float* W2 = W1 + (size_t)NCP * CH;

    make_vols<<<(V3 + 255) / 256, 256, 0, stream>>>(f50, volA, volB);

    pdd2<<<dim3(NCP, 3), 256, 0, stream>>>(f00, volA, volB, grid, alpha, W0);

    const int TOT = GS2 * CH;                      // 567675 threads for gs passes
    const int gb2 = (TOT + 255) / 256;

    pool_kernel<<<NCP, 256, 0, stream>>>(W0, W1);
    gs_z2<<<gb2, 256, 0, stream>>>(W1, W2);
    gs_y_cost2<<<gb2, 256, 0, stream>>>(W2, W0, alpha);

    pool_kernel<<<NCP, 256, 0, stream>>>(W0, W1);
    gs_z2<<<gb2, 256, 0, stream>>>(W1, W2);
    gs_y2<<<gb2, 256, 0, stream>>>(W2, out2);

    softmax_pred2<<<NCP, 256, 0, stream>>>(out2, alpha, out0, out1);
}